// Round 7
// baseline (189.778 us; speedup 1.0000x reference)
//
#include <hip/hip_runtime.h>
#include <stdint.h>

#define BATCH 16
#define H 512
#define W 512
#define HW (H * W)
#define NTOT (BATCH * HW)
#define NWORDS (NTOT / 64)      // 65536 packed words, 8 per row, 4096 per image

#define SROWS 16                // CCL strip = 16 rows
#define SWORDS 128              // words per CCL strip
#define SPIX 8192               // pixels per CCL strip
#define NSTRIPS (NWORDS / SWORDS)   // 512 strips (never straddle images)
#define IMG_STRIPS 32               // strips per image

#define MAXR 4096                   // max runs per strip (128 words x 32)
#define NR (NSTRIPS * MAXR)         // run-id space: 2M ids, 8 MB per array

#define SPIN_LIMIT (1 << 20)        // hang-insurance: give up loudly, not hang

// Persistent barrier flags (module lifetime, zero-init). Monotone epochs make
// them self-resetting across launches -> no host memset dispatch needed.
__device__ int g_flags[BATCH * 32];

// ---------------------------------------------------------------------------
// Agent-scope relaxed accessors (coherence-point). Proven r3/r4: relaxed agent
// atomics are individually coherent across XCDs with NO fences (fence removal
// cut 269->135us). r6 proved traffic isn't the floor (FETCH 40->15MB, time
// ~same): the floor is SERIAL sc1 round-trip chains. r7 shortens the chains:
// LDS-source own-strip data (0 RT), 4-wide MLP batching of L/sizes lookups.
// ---------------------------------------------------------------------------
__device__ __forceinline__ int ald(const int* p) {
    return __hip_atomic_load((int*)p, __ATOMIC_RELAXED, __HIP_MEMORY_SCOPE_AGENT);
}
__device__ __forceinline__ void ast(int* p, int v) {
    __hip_atomic_store(p, v, __ATOMIC_RELAXED, __HIP_MEMORY_SCOPE_AGENT);
}
__device__ __forceinline__ uint64_t ald64(const uint64_t* p) {
    return __hip_atomic_load((uint64_t*)p, __ATOMIC_RELAXED, __HIP_MEMORY_SCOPE_AGENT);
}
__device__ __forceinline__ void ast64(uint64_t* p, uint64_t v) {
    __hip_atomic_store(p, v, __ATOMIC_RELAXED, __HIP_MEMORY_SCOPE_AGENT);
}

// ---------------------------------------------------------------------------
// Union-find over run ids (global): atomicMin keeps parent <= child -> acyclic.
// ---------------------------------------------------------------------------
__device__ __forceinline__ int find_root_c(int* L, int x) {
    int r = x, p = ald(&L[r]);
    while (p != r) { r = p; p = ald(&L[r]); }
    if (ald(&L[x]) != r) atomicMin(&L[x], r);
    return r;
}

__device__ void merge_uf(int* L, int a, int b) {
    while (true) {
        a = find_root_c(L, a);
        b = find_root_c(L, b);
        if (a == b) return;
        int lo = a < b ? a : b;
        int hi = a < b ? b : a;
        int old = atomicMin(&L[hi], lo);
        if (old == hi) return;
        a = lo; b = old;
    }
}

__device__ __forceinline__ int find_root_lds(int* P, int x) {
    int r = x, p = P[r];
    while (p != r) { r = p; p = P[r]; }
    return r;
}

__device__ void merge_lds(int* P, int a, int b) {
    while (true) {
        a = find_root_lds(P, a);
        b = find_root_lds(P, b);
        if (a == b) return;
        int lo = a < b ? a : b;
        int hi = a < b ? b : a;
        int old = atomicMin(&P[hi], lo);
        if (old == hi) return;
        a = lo; b = old;
    }
}

// rid of the run containing bit i of word m; cvrid = global rid continuing in,
// wr = global rid of the word's first NEW run.
__device__ __forceinline__ int run_of(uint64_t m, int i, int cvrid, int wr) {
    uint64_t below = i ? ((~m) & ((1ull << i) - 1)) : 0ull;
    if (below == 0) return (cvrid >= 0) ? cvrid : wr;
    int s = 64 - __builtin_clzll(below);           // start bit of i's run
    uint64_t starts = m & ~((m << 1) | ((cvrid >= 0) ? 1ull : 0ull));
    return wr + __popcll(starts & ((1ull << s) - 1));
}

__device__ __forceinline__ int run_of_lds(uint64_t m, int i, int cvrid,
                                          uint64_t starts, int wb) {
    uint64_t below = i ? ((~m) & ((1ull << i) - 1)) : 0ull;
    if (below == 0) return (cvrid >= 0) ? cvrid : wb;
    int s = 64 - __builtin_clzll(below);
    return wb + __popcll(starts & ((1ull << s) - 1));
}

// LDS hash insert (per-block size aggregation), global fallback
__device__ __forceinline__ void hash_add(int* hk, int* hv, int* sizes,
                                         int r, int cnt) {
    uint32_t h = ((uint32_t)r * 2654435761u) >> 25;
    for (int tt = 0; tt < 16; ++tt) {
        int slot = (h + tt) & 127;
        int k = hk[slot];
        if (k == -1) k = atomicCAS(&hk[slot], -1, r);
        if (k == -1 || k == r) { atomicAdd(&hv[slot], cnt); return; }
    }
    atomicAdd(&sizes[r], cnt);
}

// ---------------------------------------------------------------------------
// keep_core: remove-small transform of one word. MLP-batched: enumerate up to
// 4 pieces (registers, full unroll), issue 4 independent L loads, then 4
// independent sizes loads (2 serial RTs total), serial tail for >4 runs.
// Relies on flatten having path-compressed every enumerated rid to its root.
// ---------------------------------------------------------------------------
__device__ uint64_t keep_core(uint64_t m, int cvg, int wrg, int nc,
                              const int* L, const int* sizes, int minsz) {
    uint64_t res = m;
    if (!m) return res;
    uint64_t rem = m;
    uint64_t pc[4]; int rd[4];
    int rk = 0;
#pragma unroll
    for (int k = 0; k < 4; ++k) {
        pc[k] = 0; rd[k] = wrg;
        if (rem) {
            int s = __builtin_ctzll(rem);
            uint64_t rest = rem >> s;
            uint64_t nr = ~rest;
            int len = nr ? __builtin_ctzll(nr) : (64 - s);
            uint64_t piece = ((len >= 64) ? ~0ull : ((1ull << len) - 1)) << s;
            bool initial = !(s == 0 && cvg >= 0);
            pc[k] = piece;
            rd[k] = initial ? (wrg + rk) : cvg;
            rk += initial ? 1 : 0;
            rem &= ~piece;
        }
    }
    int rt[4], sz[4];
#pragma unroll
    for (int k = 0; k < 4; ++k) rt[k] = ald(&L[rd[k]]);     // independent
#pragma unroll
    for (int k = 0; k < 4; ++k) {
        int idx = pc[k] ? rt[k] : rd[k];                    // guard poison roots
        sz[k] = ald(&sizes[idx]);                           // independent
    }
    if (nc > 1) {
#pragma unroll
        for (int k = 0; k < 4; ++k)
            if (pc[k] && sz[k] < minsz) res &= ~pc[k];
        while (rem) {                                       // rare tail
            int s = __builtin_ctzll(rem);
            uint64_t rest = rem >> s;
            uint64_t nr = ~rest;
            int len = nr ? __builtin_ctzll(nr) : (64 - s);
            uint64_t piece = ((len >= 64) ? ~0ull : ((1ull << len) - 1)) << s;
            int rid = wrg + rk++;                           // tail always initial
            if (ald(&sizes[ald(&L[rid])]) < minsz) res &= ~piece;
            rem &= ~piece;
        }
    }
    return res;
}

// fill_core: fill-holes transform (bg pieces), same batching; bg rid space.
__device__ uint64_t fill_core(uint64_t fg, int cvg, int wrg,
                              const int* L, const int* sizes, int minsz) {
    uint64_t bg = ~fg;
    uint64_t res = fg;
    if (!bg) return res;
    uint64_t rem = bg;
    uint64_t pc[4]; int rd[4];
    int rk = 0;
#pragma unroll
    for (int k = 0; k < 4; ++k) {
        pc[k] = 0; rd[k] = wrg;
        if (rem) {
            int s = __builtin_ctzll(rem);
            uint64_t rest = rem >> s;
            uint64_t nr = ~rest;
            int len = nr ? __builtin_ctzll(nr) : (64 - s);
            uint64_t piece = ((len >= 64) ? ~0ull : ((1ull << len) - 1)) << s;
            bool initial = !(s == 0 && cvg >= 0);
            pc[k] = piece;
            rd[k] = initial ? (wrg + rk) : cvg;
            rk += initial ? 1 : 0;
            rem &= ~piece;
        }
    }
    int rt[4], sz[4];
#pragma unroll
    for (int k = 0; k < 4; ++k) rt[k] = ald(&L[rd[k]]);
#pragma unroll
    for (int k = 0; k < 4; ++k) {
        int idx = pc[k] ? rt[k] : rd[k];
        sz[k] = ald(&sizes[idx]);
    }
#pragma unroll
    for (int k = 0; k < 4; ++k)
        if (pc[k] && sz[k] < minsz) res |= pc[k];
    while (rem) {
        int s = __builtin_ctzll(rem);
        uint64_t rest = rem >> s;
        uint64_t nr = ~rest;
        int len = nr ? __builtin_ctzll(nr) : (64 - s);
        uint64_t piece = ((len >= 64) ? ~0ull : ((1ull << len) - 1)) << s;
        int rid = wrg + rk++;
        if (ald(&sizes[ald(&L[rid])]) < minsz) res |= piece;
        rem &= ~piece;
    }
    return res;
}

// flatten_fast: per-word find_root + size accumulation. Batches the first two
// UF hops 4-wide; serial walk only for depth>2 (rare). Path-compresses rids.
__device__ void flatten_fast(uint64_t m, int cvg, int wrg,
                             int* L, int* sizes, int* ncomp_img,
                             int t, int* hk, int* hv) {
    if (t < 128) { hk[t] = -1; hv[t] = 0; }
    __syncthreads();
    if (t < SWORDS && m) {
        uint64_t rem = m;
        uint64_t pc[4]; int rd[4]; bool ini[4];
        int rk = 0;
#pragma unroll
        for (int k = 0; k < 4; ++k) {
            pc[k] = 0; rd[k] = wrg; ini[k] = false;
            if (rem) {
                int s = __builtin_ctzll(rem);
                uint64_t rest = rem >> s;
                uint64_t nr = ~rest;
                int len = nr ? __builtin_ctzll(nr) : (64 - s);
                uint64_t piece = ((len >= 64) ? ~0ull : ((1ull << len) - 1)) << s;
                bool initial = !(s == 0 && cvg >= 0);
                pc[k] = piece;
                rd[k] = initial ? (wrg + rk) : cvg;
                ini[k] = initial;
                rk += initial ? 1 : 0;
                rem &= ~piece;
            }
        }
        int h1[4], h2[4];
#pragma unroll
        for (int k = 0; k < 4; ++k) h1[k] = ald(&L[rd[k]]);
#pragma unroll
        for (int k = 0; k < 4; ++k) {
            int i1 = pc[k] ? h1[k] : rd[k];
            h2[k] = ald(&L[i1]);
        }
#pragma unroll
        for (int k = 0; k < 4; ++k) {
            if (pc[k]) {
                int r;
                if (h2[k] == h1[k]) r = h1[k];
                else {
                    r = h2[k];
                    int p = ald(&L[r]);
                    while (p != r) { r = p; p = ald(&L[r]); }
                }
                if (h1[k] != r) atomicMin(&L[rd[k]], r);
                if (ini[k] && r == rd[k]) atomicAdd(ncomp_img, 1);
                hash_add(hk, hv, sizes, r, __popcll(pc[k]));
            }
        }
        while (rem) {
            int s = __builtin_ctzll(rem);
            uint64_t rest = rem >> s;
            uint64_t nr = ~rest;
            int len = nr ? __builtin_ctzll(nr) : (64 - s);
            uint64_t piece = ((len >= 64) ? ~0ull : ((1ull << len) - 1)) << s;
            int rid = wrg + rk++;
            int r = find_root_c(L, rid);
            if (r == rid) atomicAdd(ncomp_img, 1);
            hash_add(hk, hv, sizes, r, __popcll(piece));
            rem &= ~piece;
        }
    }
    __syncthreads();
    if (t < 128 && hk[t] != -1) atomicAdd(&sizes[hk[t]], hv[t]);
}

// one morph output word from an LDS window; gyTop = global row of local row 0
template <int R, bool ERODE>
__device__ uint64_t morph_word_lds(const uint64_t* buf, int lrow, int w, int gyTop) {
    const uint64_t BORDER = ERODE ? ~0ull : 0ull;
    uint64_t res = ERODE ? ~0ull : 0ull;
#pragma unroll
    for (int dy = -R; dy <= R; ++dy) {
        int lr = lrow + dy;
        int gy = gyTop + lr;
        if (gy < 0 || gy >= H) continue;       // image border rows = identity
        int v = R * R - dy * dy;
        int kx = 0;
        while ((kx + 1) * (kx + 1) <= v) ++kx;
        uint64_t cur = buf[lr * 8 + w];
        uint64_t prv = (w > 0) ? buf[lr * 8 + w - 1] : BORDER;
        uint64_t nxt = (w < 7) ? buf[lr * 8 + w + 1] : BORDER;
        uint64_t acc = cur;
#pragma unroll
        for (int dx = 1; dx <= kx; ++dx) {
            uint64_t right = (cur >> dx) | (nxt << (64 - dx));
            uint64_t left  = (cur << dx) | (prv >> (64 - dx));
            if (ERODE) acc &= right & left;
            else       acc |= right | left;
        }
        if (ERODE) res &= acc;
        else       res |= acc;
    }
    return res;
}

// ---------------------------------------------------------------------------
// Strip-local CCL body, run-id edition (blockDim 256; t >= SWORDS pass m = 0).
// LDS side-products scarry/cntL/wbL PERSIST after return and are reused by the
// following phases (zero-RT rid resolution for own-strip words).
// ---------------------------------------------------------------------------
__device__ void strip_ccl_body(uint64_t m, uint64_t* sw, int* scarry,
                               int* cntL, int* wbL, int* par,
                               int blk, int t,
                               int* __restrict__ carry, int* __restrict__ wordrun,
                               int* __restrict__ L, int* __restrict__ sizes,
                               int* __restrict__ ncomp) {
    if (t < SWORDS) sw[t] = m;
    __syncthreads();

    if (t < SWORDS) {                   // per-word new-run count
        bool cont = (t & 7) ? ((sw[t - 1] >> 63) != 0) : false;
        int c = __popcll(m & ~(m << 1));
        if ((m & 1ull) && cont) --c;
        cntL[t] = c;
        wbL[t] = c;
    }
    __syncthreads();
    for (int off = 1; off < SWORDS; off <<= 1) {   // inclusive scan (128)
        int v = 0;
        if (t < SWORDS && t >= off) v = wbL[t - off];
        __syncthreads();
        if (t < SWORDS) wbL[t] += v;
        __syncthreads();
    }

    if (t < SROWS) {                    // per-row rid carries
        int cv = -1;
        for (int i = 0; i < 8; ++i) {
            int lw = t * 8 + i;
            scarry[lw] = cv;
            uint64_t w = sw[lw];
            if (w >> 63) { if (cntL[lw] > 0) cv = wbL[lw] - 1; }  // last start's rid
            else cv = -1;
        }
    }
    for (int i = t; i < MAXR; i += 256) par[i] = i;   // identity init
    __syncthreads();

    int cv = -1, wb = 0;
    uint64_t starts = 0ull;
    if (t < SWORDS) {
        cv = scarry[t];
        wb = wbL[t] - cntL[t];          // exclusive base
        ast(&carry[blk * SWORDS + t], (cv >= 0) ? (blk * MAXR + cv) : -1);
        ast(&wordrun[blk * SWORDS + t], blk * MAXR + wb);
        starts = m & ~((m << 1) | ((cv >= 0) ? 1ull : 0ull));
    }
    __syncthreads();

    if (t >= 8 && t < SWORDS && m) {    // intra-strip vertical unions
        uint64_t up = sw[t - 8];
        uint64_t cand = m & up;
        if (cand) {
            uint64_t curprev = (t & 7) ? sw[t - 1] : 0ull;
            uint64_t upprev  = (t & 7) ? sw[t - 9] : 0ull;
            uint64_t curl = (m << 1) | (curprev >> 63);
            uint64_t upl  = (up << 1) | (upprev >> 63);
            cand &= ~(curl & upl);
            int cvu = scarry[t - 8];
            int wbu = wbL[t - 8] - cntL[t - 8];
            uint64_t startsU = up & ~((up << 1) | ((cvu >= 0) ? 1ull : 0ull));
            while (cand) {
                int i = __builtin_ctzll(cand);
                int sP = run_of_lds(m, i, cv, starts, wb);
                int sQ = run_of_lds(up, i, cvu, startsU, wbu);
                merge_lds(par, sP, sQ);
                cand &= cand - 1;
            }
        }
    }
    __syncthreads();

    if (t < SWORDS) {                   // publish depth-1 trees (rid space)
        int g = blk * MAXR;
        uint64_t ss = starts;
        int rk = 0;
        while (ss) {
            int rid = wb + rk; ++rk;
            int r = find_root_lds(par, rid);
            ast(&L[g + rid], g + r);
            if (r == rid) ast(&sizes[g + rid], 0);
            ss &= ss - 1;
        }
    }
    if (t == 0 && (blk & 31) == 0) ast(&ncomp[blk >> 5], 0);  // 32 strips/image
}

// ---------------------------------------------------------------------------
// PER-IMAGE fence-free barrier with persistent epoch flags (no host memset).
// Release = __syncthreads (each wave drains its own vmcnt) + explicit vmcnt(0).
// ---------------------------------------------------------------------------
__device__ __forceinline__ void ibar(int img, int si, int ep, int phase) {
    int* base = g_flags + img * 32;
    __syncthreads();
    if (threadIdx.x == 0) {
        asm volatile("s_waitcnt vmcnt(0)" ::: "memory");
        ast(&base[si], ep + phase);
    }
    if (threadIdx.x < 32) {
        int spins = 0;
        while (ald(&base[threadIdx.x]) - ep < phase && ++spins < SPIN_LIMIT)
            __builtin_amdgcn_s_sleep(1);
    }
    __syncthreads();
}

// ---------------------------------------------------------------------------
// MEGA: whole pipeline, ONE regular kernel, 9 per-image barriers, run-id UF,
// LDS-sourced own-strip data + MLP-batched global lookups.
// ---------------------------------------------------------------------------
__global__ __launch_bounds__(256, 2) void k_mega(
        const float4* __restrict__ in4, float* __restrict__ out,
        int* LA, int* sizesA, int* LB, int* sizesB,
        uint64_t* bits1, uint64_t* bits2, uint64_t* bits3,
        int* carryA, int* carryB, int* wordrunA, int* wordrunB,
        int* ncompA, int* ncompB) {
    __shared__ uint64_t sw[SWORDS];
    __shared__ int scarry[SWORDS];
    __shared__ int cntL[SWORDS];
    __shared__ int wbL[SWORDS];
    __shared__ union US {
        int par[MAXR];                                     // 16 KB (CCL)
        struct { uint64_t A[320]; uint64_t B[320]; } mo;   // 5 KB (morph)
        struct { int hk[128]; int hv[128]; } ha;           // 1 KB (flatten hash)
        struct { uint64_t kb[80]; uint64_t db[64]; } kd;   // 1.1 KB (out stage)
    } U;
    int blk = blockIdx.x;
    int t = threadIdx.x;
    int img = blk >> 5, si = blk & 31;   // image id, strip-in-image
    int ep = ald(&g_flags[img * 32 + si]);   // epoch = own flag's last value

    // P0: threshold + pack, strip-local; words also dropped into LDS sw so P1
    // never re-reads bits1 from global.
#pragma unroll
    for (int it = 0; it < 8; ++it) {
        int q = blk * (SPIX / 4) + it * 256 + t;           // quad index
        float4 v = in4[q];
        uint32_t nib = (v.x > 0.0f ? 1u : 0u) | (v.y > 0.0f ? 2u : 0u) |
                       (v.z > 0.0f ? 4u : 0u) | (v.w > 0.0f ? 8u : 0u);
        uint64_t val = (uint64_t)nib << (4 * (t & 15));
        val |= __shfl_xor(val, 1);
        val |= __shfl_xor(val, 2);
        val |= __shfl_xor(val, 4);
        val |= __shfl_xor(val, 8);
        if ((t & 15) == 0) {
            ast64(&bits1[q >> 4], val);                    // for merge halos
            sw[it * 16 + (t >> 4)] = val;
        }
    }
    __syncthreads();

    // P1: CCL1 strip phase (fg of bits1) -> set A
    {
        uint64_t m = (t < SWORDS) ? sw[t] : 0ull;
        strip_ccl_body(m, sw, scarry, cntL, wbL, U.par, blk, t,
                       carryA, wordrunA, LA, sizesA, ncompA);
    }
    ibar(img, si, ep, 1);

    // P2: cross-strip merges (bits1, fg). Block si merges boundary below its
    // strip (rows 16si+15 | 16si+16). Up side entirely from LDS; down side =
    // 4 independent global loads (1 RT).
    if (t < 8 && si < 31) {
        int gw = (blk + 1) * SWORDS + t;     // below strip's row-0 word t
        uint64_t cur = ald64(&bits1[gw]);
        uint64_t curprev = t ? ald64(&bits1[gw - 1]) : 0ull;
        int cvc = ald(&carryA[gw]);
        int wrc = ald(&wordrunA[gw]);
        uint64_t up = sw[120 + t];
        uint64_t upprev = t ? sw[119 + t] : 0ull;
        int cvuL = scarry[120 + t];
        int cvu = cvuL >= 0 ? blk * MAXR + cvuL : -1;
        int wru = blk * MAXR + (wbL[120 + t] - cntL[120 + t]);
        uint64_t cand = cur & up;
        if (cand) {
            uint64_t curl = (cur << 1) | (curprev >> 63);
            uint64_t upl  = (up << 1) | (upprev >> 63);
            cand &= ~(curl & upl);
            while (cand) {
                int i = __builtin_ctzll(cand);
                int sP = run_of(cur, i, cvc, wrc);
                int sQ = run_of(up, i, cvu, wru);
                merge_uf(LA, sP, sQ);
                cand &= cand - 1;
            }
        }
    }
    ibar(img, si, ep, 2);

    // P3: flatten + count (fg) — m/cv/wr from LDS (P1 leftovers), 0 extra RTs
    {
        uint64_t m = (t < SWORDS) ? sw[t] : 0ull;
        int cvL = (t < SWORDS) ? scarry[t] : -1;
        int cvg = cvL >= 0 ? blk * MAXR + cvL : -1;
        int wrg = blk * MAXR + ((t < SWORDS) ? (wbL[t] - cntL[t]) : 0);
        flatten_fast(m, cvg, wrg, LA, sizesA, &ncompA[img], t, U.ha.hk, U.ha.hv);
    }
    ibar(img, si, ep, 3);

    // P4: remove_small_objects(2000,guard) -> bits2, fused with CCL2 strip (bg)
    {
        uint64_t m2 = 0ull;
        if (t < SWORDS) {
            int nc = ald(&ncompA[img]);             // issued alongside L batch
            uint64_t m1 = sw[t];
            int cvL = scarry[t];
            int cvg = cvL >= 0 ? blk * MAXR + cvL : -1;
            int wrg = blk * MAXR + (wbL[t] - cntL[t]);
            uint64_t kw = keep_core(m1, cvg, wrg, nc, LA, sizesA, 2000);
            ast64(&bits2[blk * SWORDS + t], kw);
            m2 = ~kw;
        }
        strip_ccl_body(m2, sw, scarry, cntL, wbL, U.par, blk, t,
                       carryB, wordrunB, LB, sizesB, ncompB);
    }
    ibar(img, si, ep, 4);

    // P5: cross-strip merges (bits2, bg) — sw holds the bg mask already
    if (t < 8 && si < 31) {
        int gw = (blk + 1) * SWORDS + t;
        uint64_t cur = ~ald64(&bits2[gw]);
        uint64_t curprev = t ? ~ald64(&bits2[gw - 1]) : 0ull;
        int cvc = ald(&carryB[gw]);
        int wrc = ald(&wordrunB[gw]);
        uint64_t up = sw[120 + t];
        uint64_t upprev = t ? sw[119 + t] : 0ull;
        int cvuL = scarry[120 + t];
        int cvu = cvuL >= 0 ? blk * MAXR + cvuL : -1;
        int wru = blk * MAXR + (wbL[120 + t] - cntL[120 + t]);
        uint64_t cand = cur & up;
        if (cand) {
            uint64_t curl = (cur << 1) | (curprev >> 63);
            uint64_t upl  = (up << 1) | (upprev >> 63);
            cand &= ~(curl & upl);
            while (cand) {
                int i = __builtin_ctzll(cand);
                int sP = run_of(cur, i, cvc, wrc);
                int sQ = run_of(up, i, cvu, wru);
                merge_uf(LB, sP, sQ);
                cand &= cand - 1;
            }
        }
    }
    ibar(img, si, ep, 5);

    // P6: flatten + count (bg) — LDS-sourced
    {
        uint64_t m = (t < SWORDS) ? sw[t] : 0ull;
        int cvL = (t < SWORDS) ? scarry[t] : -1;
        int cvg = cvL >= 0 ? blk * MAXR + cvL : -1;
        int wrg = blk * MAXR + ((t < SWORDS) ? (wbL[t] - cntL[t]) : 0);
        flatten_fast(m, cvg, wrg, LB, sizesB, &ncompB[img], t, U.ha.hk, U.ha.hv);
    }
    ibar(img, si, ep, 6);

    // P7: fill_holes(<301) + erode(d2) + opening(d5) + CCL3 strip -> bits3, A
    {
        int gyTop = si * 16 - 12;
        for (int lw = t; lw < 320; lw += 256) {
            int gy = gyTop + (lw >> 3);
            int w = lw & 7;
            uint64_t v = 0;
            if (gy >= 0 && gy < H) {
                uint64_t fg; int cvg, wrg;
                if (lw >= 96 && lw < 224) {          // own strip: LDS source
                    int ti = lw - 96;
                    fg = ~sw[ti];                    // sw = bg mask -> fg
                    int cvL = scarry[ti];
                    cvg = cvL >= 0 ? blk * MAXR + cvL : -1;
                    wrg = blk * MAXR + (wbL[ti] - cntL[ti]);
                } else {                             // halo: 3 parallel loads
                    int gw = img * 4096 + gy * 8 + w;
                    fg = ald64(&bits2[gw]);
                    cvg = ald(&carryB[gw]);
                    wrg = ald(&wordrunB[gw]);
                }
                v = fill_core(fg, cvg, wrg, LB, sizesB, 301);
            }
            U.mo.A[lw] = v;
        }
        __syncthreads();
        for (int lw = t; lw < 320; lw += 256) {              // erode disk(2)
            int lr = lw >> 3;
            if (lr >= 2 && lr <= 37) U.mo.B[lw] = morph_word_lds<2, true>(U.mo.A, lr, lw & 7, gyTop);
        }
        __syncthreads();
        for (int lw = t; lw < 320; lw += 256) {              // erode disk(5)
            int lr = lw >> 3;
            if (lr >= 7 && lr <= 32) U.mo.A[lw] = morph_word_lds<5, true>(U.mo.B, lr, lw & 7, gyTop);
        }
        __syncthreads();
        for (int lw = t; lw < 320; lw += 256) {              // dilate disk(5)
            int lr = lw >> 3;
            if (lr >= 12 && lr <= 27) U.mo.B[lw] = morph_word_lds<5, false>(U.mo.A, lr, lw & 7, gyTop);
        }
        __syncthreads();
        uint64_t m3 = 0ull;
        if (t < SWORDS) {
            m3 = U.mo.B[t + 96];        // local rows 12..27 = this strip
            ast64(&bits3[blk * SWORDS + t], m3);
        }
        // par aliases mo — safe: all mo.B reads (m3) happen before body's first
        // par write, which is behind multiple __syncthreads
        strip_ccl_body(m3, sw, scarry, cntL, wbL, U.par, blk, t,
                       carryA, wordrunA, LA, sizesA, ncompA);
    }
    ibar(img, si, ep, 7);

    // P8: cross-strip merges (bits3, fg)
    if (t < 8 && si < 31) {
        int gw = (blk + 1) * SWORDS + t;
        uint64_t cur = ald64(&bits3[gw]);
        uint64_t curprev = t ? ald64(&bits3[gw - 1]) : 0ull;
        int cvc = ald(&carryA[gw]);
        int wrc = ald(&wordrunA[gw]);
        uint64_t up = sw[120 + t];
        uint64_t upprev = t ? sw[119 + t] : 0ull;
        int cvuL = scarry[120 + t];
        int cvu = cvuL >= 0 ? blk * MAXR + cvuL : -1;
        int wru = blk * MAXR + (wbL[120 + t] - cntL[120 + t]);
        uint64_t cand = cur & up;
        if (cand) {
            uint64_t curl = (cur << 1) | (curprev >> 63);
            uint64_t upl  = (up << 1) | (upprev >> 63);
            cand &= ~(curl & upl);
            while (cand) {
                int i = __builtin_ctzll(cand);
                int sP = run_of(cur, i, cvc, wrc);
                int sQ = run_of(up, i, cvu, wru);
                merge_uf(LA, sP, sQ);
                cand &= cand - 1;
            }
        }
    }
    ibar(img, si, ep, 8);

    // P9: flatten + count (bits3, fg) — LDS-sourced
    {
        uint64_t m = (t < SWORDS) ? sw[t] : 0ull;
        int cvL = (t < SWORDS) ? scarry[t] : -1;
        int cvg = cvL >= 0 ? blk * MAXR + cvL : -1;
        int wrg = blk * MAXR + ((t < SWORDS) ? (wbL[t] - cntL[t]) : 0);
        flatten_fast(m, cvg, wrg, LA, sizesA, &ncompA[img], t, U.ha.hk, U.ha.hv);
    }
    ibar(img, si, ep, 9);

    // P10: remove_small_objects(2000,guard) + dilate(d1) + float4 out.
    // 2 segs per block; own-strip rows from LDS, 2 halo rows from global.
    for (int k = 0; k < 2; ++k) {
        int s8 = 2 * si + k;
        int y0 = s8 * 8;
        if (t < 80) {
            int lr = t >> 3, w = t & 7;
            int gy = y0 - 1 + lr;
            uint64_t v = 0;
            if (gy >= 0 && gy < H) {
                int nc = ald(&ncompA[img]);
                uint64_t m; int cvg, wrg;
                int rel = gy - 16 * si;
                if (rel >= 0 && rel < 16) {          // own strip: LDS source
                    int ti = rel * 8 + w;
                    m = sw[ti];
                    int cvL = scarry[ti];
                    cvg = cvL >= 0 ? blk * MAXR + cvL : -1;
                    wrg = blk * MAXR + (wbL[ti] - cntL[ti]);
                } else {                             // halo row
                    int gw = img * 4096 + gy * 8 + w;
                    m = ald64(&bits3[gw]);
                    cvg = ald(&carryA[gw]);
                    wrg = ald(&wordrunA[gw]);
                }
                v = keep_core(m, cvg, wrg, nc, LA, sizesA, 2000);
            }
            U.kd.kb[t] = v;
        }
        __syncthreads();
        if (t < 64) {
            int r = t >> 3, w = t & 7;
            uint64_t cur = U.kd.kb[(r + 1) * 8 + w];
            uint64_t up  = U.kd.kb[r * 8 + w];
            uint64_t dn  = U.kd.kb[(r + 2) * 8 + w];
            uint64_t prv = w ? U.kd.kb[(r + 1) * 8 + w - 1] : 0ull;
            uint64_t nxt = (w < 7) ? U.kd.kb[(r + 1) * 8 + w + 1] : 0ull;
            U.kd.db[t] = cur | up | dn | (cur << 1) | (prv >> 63) |
                         (cur >> 1) | (nxt << 63);
        }
        __syncthreads();
        {
            int q0 = t * 16;                    // 16 consecutive pixels/thread
            uint64_t wd = U.kd.db[q0 >> 6];
            int sh = q0 & 63;
            float4* o = (float4*)(out + (size_t)img * HW + (size_t)y0 * W + q0);
#pragma unroll
            for (int kk = 0; kk < 4; ++kk) {
                uint32_t nib = (uint32_t)(wd >> (sh + kk * 4)) & 0xFu;
                float4 f;
                f.x = (nib & 1u) ? 1.0f : 0.0f;
                f.y = (nib & 2u) ? 1.0f : 0.0f;
                f.z = (nib & 4u) ? 1.0f : 0.0f;
                f.w = (nib & 8u) ? 1.0f : 0.0f;
                o[kk] = f;
            }
        }
        __syncthreads();
    }
}

// ---------------------------------------------------------------------------
// Host side — exactly ONE dispatch (flags are persistent device globals)
// ---------------------------------------------------------------------------
extern "C" void kernel_launch(void* const* d_in, const int* in_sizes, int n_in,
                              void* d_out, int out_size, void* d_ws, size_t ws_size,
                              hipStream_t stream) {
    const float* in = (const float*)d_in[0];
    float* out = (float*)d_out;

    uint8_t* ws = (uint8_t*)d_ws;
    int* LA      = (int*)ws;                                  // 8 MB (rid space)
    int* sizesA  = LA + NR;                                   // 8 MB
    int* LB      = sizesA + NR;                               // 8 MB
    int* sizesB  = LB + NR;                                   // 8 MB
    uint64_t* bits1 = (uint64_t*)(sizesB + NR);               // 512 KB
    uint64_t* bits2 = bits1 + NWORDS;                         // 512 KB
    uint64_t* bits3 = bits2 + NWORDS;                         // 512 KB
    int* carryA   = (int*)(bits3 + NWORDS);                   // 256 KB
    int* carryB   = carryA + NWORDS;                          // 256 KB
    int* wordrunA = carryB + NWORDS;                          // 256 KB
    int* wordrunB = wordrunA + NWORDS;                        // 256 KB
    int* ncompA   = wordrunB + NWORDS;                        // 64 B
    int* ncompB   = ncompA + BATCH;                           // 64 B

    k_mega<<<NSTRIPS, 256, 0, stream>>>((const float4*)in, out,
                                        LA, sizesA, LB, sizesB,
                                        bits1, bits2, bits3,
                                        carryA, carryB, wordrunA, wordrunB,
                                        ncompA, ncompB);
}